// Round 2
// baseline (54186.932 us; speedup 1.0000x reference)
//
#include <hip/hip_runtime.h>

#define Bsz  4
#define Lsz  4096
#define Csz  1024
#define NHsz 16
#define CSsz 16
#define HFsz 64
#define HF4sz 256
#define NCsz 256

// ---------------------------------------------------------------------------
// fp32 GEMM: C[M,N] = A[M,K] @ B[K,N].  64x64 tile, BK=16, 4x4 microtile.
// ---------------------------------------------------------------------------
__global__ __launch_bounds__(256)
void gemm64(const float* __restrict__ A, const float* __restrict__ Bm,
            float* __restrict__ Cm, int M, int N, int K)
{
  __shared__ __attribute__((aligned(16))) float As[16][68];
  __shared__ __attribute__((aligned(16))) float Bs[16][64];
  const int t  = threadIdx.x;
  const int tx = t & 15, ty = t >> 4;
  const int row0 = blockIdx.y * 64, col0 = blockIdx.x * 64;
  const int ar = t >> 2, ak = (t & 3) * 4;   // A staging: row, k-offset
  const int bk = t >> 4, bc = (t & 15) * 4;  // B staging: k, col-offset
  float acc[4][4] = {};

  for (int k0 = 0; k0 < K; k0 += 16) {
    float4 a4 = *(const float4*)&A[(size_t)(row0 + ar) * K + k0 + ak];
    float4 b4 = *(const float4*)&Bm[(size_t)(k0 + bk) * N + col0 + bc];
    As[ak + 0][ar] = a4.x; As[ak + 1][ar] = a4.y;
    As[ak + 2][ar] = a4.z; As[ak + 3][ar] = a4.w;
    *(float4*)&Bs[bk][bc] = b4;
    __syncthreads();
#pragma unroll
    for (int kk = 0; kk < 16; ++kk) {
      float4 av = *(const float4*)&As[kk][ty * 4];
      float4 bv = *(const float4*)&Bs[kk][tx * 4];
      acc[0][0] += av.x * bv.x; acc[0][1] += av.x * bv.y;
      acc[0][2] += av.x * bv.z; acc[0][3] += av.x * bv.w;
      acc[1][0] += av.y * bv.x; acc[1][1] += av.y * bv.y;
      acc[1][2] += av.y * bv.z; acc[1][3] += av.y * bv.w;
      acc[2][0] += av.z * bv.x; acc[2][1] += av.z * bv.y;
      acc[2][2] += av.z * bv.z; acc[2][3] += av.z * bv.w;
      acc[3][0] += av.w * bv.x; acc[3][1] += av.w * bv.y;
      acc[3][2] += av.w * bv.z; acc[3][3] += av.w * bv.w;
    }
    __syncthreads();
  }
#pragma unroll
  for (int r = 0; r < 4; ++r) {
    float4 v = make_float4(acc[r][0], acc[r][1], acc[r][2], acc[r][3]);
    *(float4*)&Cm[(size_t)(row0 + ty * 4 + r) * N + col0 + tx * 4] = v;
  }
}

// ---------------------------------------------------------------------------
// ilr: logit[r,h] = sum_k H[r,k]*Wil[k,h];  coeff[b,h,nc,cs] =
//   sigmoid(logit + bil[h]) / ((cs+1)*HF).   One block = 4 rows.
// ---------------------------------------------------------------------------
__global__ __launch_bounds__(256)
void ilr_coeff(const float* __restrict__ H, const float* __restrict__ Wil,
               const float* __restrict__ bil, float* __restrict__ coeff)
{
  __shared__ float sRow[4][1024];
  __shared__ float sP[4][16][17];
  const int t = threadIdx.x;
  const size_t r0 = (size_t)blockIdx.x * 4;
  for (int rr = 0; rr < 4; ++rr)
    for (int c = t; c < 1024; c += 256)
      sRow[rr][c] = H[(r0 + rr) * 1024 + c];
  __syncthreads();
  const int hh = t & 15, sl = t >> 4;
  for (int rr = 0; rr < 4; ++rr) {
    float acc = 0.f;
    for (int kk = 0; kk < 64; ++kk)
      acc += sRow[rr][sl * 64 + kk] * Wil[(sl * 64 + kk) * 16 + hh];
    sP[rr][sl][hh] = acc;
  }
  __syncthreads();
  if (t < 64) {
    const int rr = t >> 4, h2 = t & 15;
    float s = 0.f;
    for (int sl2 = 0; sl2 < 16; ++sl2) s += sP[rr][sl2][h2];
    s += bil[h2];
    const float sig = 1.f / (1.f + expf(-s));
    const int r  = (int)(r0 + rr);
    const int b  = r >> 12, l = r & 4095, nc = l >> 4, cs = l & 15;
    coeff[((b * 16 + h2) * NCsz + nc) * CSsz + cs] = sig / ((float)(cs + 1) * 64.0f);
  }
}

// ---------------------------------------------------------------------------
// Sequential TTT scan.  One block per (b,h); 256 threads.
// W1 column n=t in regs (only ever column-accessed).
// W2 in regs twice: row copy (row n=t) and column copy (col m=t&63, quarter q=t>>6).
// ---------------------------------------------------------------------------
__global__ __launch_bounds__(256, 1)
void ttt_scan(const float* __restrict__ XA, const float* __restrict__ XBuf,
              const float* __restrict__ XCbuf, const float* __restrict__ coeff,
              const float* __restrict__ W1g, const float* __restrict__ W2g,
              float* __restrict__ Out)
{
  __shared__ __attribute__((aligned(16))) float sXB[16 * 68];
  __shared__ __attribute__((aligned(16))) float sXC[16 * 68];
  __shared__ __attribute__((aligned(16))) float sg2[16 * 68];
  __shared__ __attribute__((aligned(16))) float sZ1[16 * 260];
  __shared__ __attribute__((aligned(16))) float sZ1b[16 * 260];
  __shared__ float sA1[256];
  __shared__ float sA2[256];
  __shared__ float sRed[4 * 16 * 64];
  __shared__ float sCo[16];

  const int t  = threadIdx.x;
  const int bh = blockIdx.x;              // 0..63
  const int b  = bh >> 4, h = bh & 15;
  const int n  = t;                       // 0..255 : 4HF column
  const int m  = t & 63, q = t >> 6;      // HF column, quarter
  const int ia = t >> 4, ja = t & 15;     // attn element

  float w1[64];   // W1[k][n],            k  = 0..63
  float w2r[64];  // W2[n][mm],           mm = 0..63   (row copy)
  float w2c[64];  // W2[q*64+kk][m],      kk = 0..63   (col copy)
  float z1v[16];  // Z1[:, n]
  float g1r[16];  // g1[:, n]

  const float* W1h = W1g + h * HFsz * HF4sz;
  const float* W2h = W2g + h * HF4sz * HFsz;
#pragma unroll
  for (int k = 0; k < 64; ++k)  w1[k]  = W1h[k * 256 + n];
#pragma unroll
  for (int mm = 0; mm < 64; ++mm) w2r[mm] = W2h[n * 64 + mm];
#pragma unroll
  for (int kk = 0; kk < 64; ++kk) w2c[kk] = W2h[(q * 64 + kk) * 64 + m];

  const int cs0 = t >> 6, fld = t & 63;

#pragma unroll 1
  for (int nc = 0; nc < NCsz; ++nc) {
    const int cb = (b * Lsz + nc * CSsz) * Csz + h * HFsz;  // chunk base in (B,L,C)

    // ---- stage XB, XC chunk (16x64) and coeff ---------------------------
#pragma unroll
    for (int j = 0; j < 4; ++j) {
      const int cs = cs0 * 4 + j;
      sXB[cs * 68 + fld] = XBuf[cb + cs * Csz + fld];
      sXC[cs * 68 + fld] = XCbuf[cb + cs * Csz + fld];
    }
    if (t < 16) sCo[t] = coeff[(bh * NCsz + nc) * CSsz + t];
    __syncthreads();
    const float cl = sCo[15];  // coeff_last (scalar per chunk)

    // ---- Z1 = XB @ W1  (column n); Attn1 = tril(XC @ XB^T) --------------
#pragma unroll
    for (int i = 0; i < 16; ++i) {
      float acc = 0.f;
#pragma unroll
      for (int k = 0; k < 64; k += 4) {
        float4 x = *(const float4*)&sXB[i * 68 + k];
        acc += x.x * w1[k] + x.y * w1[k + 1] + x.z * w1[k + 2] + x.w * w1[k + 3];
      }
      z1v[i] = acc;
      sZ1[i * 260 + n] = acc;
    }
    {
      float acc = 0.f;
      if (ja <= ia)
        for (int k = 0; k < 64; ++k) acc += sXC[ia * 68 + k] * sXB[ja * 68 + k];
      sA1[ia * 16 + ja] = acc;    // zeros above diagonal
    }
    __syncthreads();

    // ---- Z2 partials: thread (m,q) over its K-quarter -------------------
#pragma unroll
    for (int i = 0; i < 16; ++i) {
      float acc = 0.f;
#pragma unroll
      for (int kk = 0; kk < 64; kk += 4) {
        float4 z = *(const float4*)&sZ1[i * 260 + q * 64 + kk];
        acc += z.x * w2c[kk] + z.y * w2c[kk + 1] + z.z * w2c[kk + 2] + z.w * w2c[kk + 3];
      }
      sRed[(q * 16 + i) * 64 + m] = acc;
    }
    __syncthreads();

    // ---- g2 = Z2 - XA ---------------------------------------------------
#pragma unroll
    for (int r = 0; r < 4; ++r) {
      const int i = q + 4 * r;
      float v = sRed[i * 64 + m] + sRed[(16 + i) * 64 + m]
              + sRed[(32 + i) * 64 + m] + sRed[(48 + i) * 64 + m];
      v -= XA[cb + i * Csz + m];
      sg2[i * 68 + m] = v;
    }
    __syncthreads();

    // ---- g1 col n = g2 @ W2^T  (row copy) -------------------------------
#pragma unroll
    for (int i = 0; i < 16; ++i) {
      float acc = 0.f;
#pragma unroll
      for (int mm = 0; mm < 64; mm += 4) {
        float4 g = *(const float4*)&sg2[i * 68 + mm];
        acc += g.x * w2r[mm] + g.y * w2r[mm + 1] + g.z * w2r[mm + 2] + g.w * w2r[mm + 3];
      }
      g1r[i] = acc;
    }
    // ---- Z1b col n = XC @ W1 - coeff * (Attn1 @ g1)  (old W1) -----------
#pragma unroll
    for (int i = 0; i < 16; ++i) {
      float acc = 0.f;
#pragma unroll
      for (int k = 0; k < 64; k += 4) {
        float4 x = *(const float4*)&sXC[i * 68 + k];
        acc += x.x * w1[k] + x.y * w1[k + 1] + x.z * w1[k + 2] + x.w * w1[k + 3];
      }
      float at = 0.f;
#pragma unroll
      for (int j = 0; j < 16; ++j)
        if (j <= i) at += sA1[i * 16 + j] * g1r[j];
      sZ1b[i * 260 + n] = acc - sCo[i] * at;
    }
    // ---- W1[k][n] -= cl * sum_i XB[i][k] * g1[i][n] ---------------------
#pragma unroll
    for (int i = 0; i < 16; ++i) {
      const float s = cl * g1r[i];
#pragma unroll
      for (int k = 0; k < 64; k += 4) {
        float4 x = *(const float4*)&sXB[i * 68 + k];
        w1[k]     -= s * x.x; w1[k + 1] -= s * x.y;
        w1[k + 2] -= s * x.z; w1[k + 3] -= s * x.w;
      }
    }
    __syncthreads();

    // ---- Attn2 = tril(Z1b @ Z1^T), K=256 --------------------------------
    {
      float acc = 0.f;
      if (ja <= ia)
        for (int kk = 0; kk < 256; ++kk)
          acc += sZ1b[ia * 260 + kk] * sZ1[ja * 260 + kk];
      sA2[ia * 16 + ja] = acc;
    }
    __syncthreads();

    // ---- Z2b partials (old W2 col copy) ---------------------------------
#pragma unroll
    for (int i = 0; i < 16; ++i) {
      float acc = 0.f;
#pragma unroll
      for (int kk = 0; kk < 64; kk += 4) {
        float4 z = *(const float4*)&sZ1b[i * 260 + q * 64 + kk];
        acc += z.x * w2c[kk] + z.y * w2c[kk + 1] + z.z * w2c[kk + 2] + z.w * w2c[kk + 3];
      }
      sRed[(q * 16 + i) * 64 + m] = acc;
    }
    __syncthreads();

    // ---- Z2b combine + store --------------------------------------------
#pragma unroll
    for (int r = 0; r < 4; ++r) {
      const int i = q + 4 * r;
      float v = sRed[i * 64 + m] + sRed[(16 + i) * 64 + m]
              + sRed[(32 + i) * 64 + m] + sRed[(48 + i) * 64 + m];
      float at = 0.f;
      for (int j = 0; j < 16; ++j) at += sA2[i * 16 + j] * sg2[j * 68 + m];
      Out[cb + i * Csz + m] = v - sCo[i] * at;
    }
    // ---- W2 row copy update: W2[n][mm] -= cl * sum_i Z1[i][n] g2[i][mm] -
#pragma unroll
    for (int i = 0; i < 16; ++i) {
      const float s = cl * z1v[i];
#pragma unroll
      for (int mm = 0; mm < 64; mm += 4) {
        float4 g = *(const float4*)&sg2[i * 68 + mm];
        w2r[mm]     -= s * g.x; w2r[mm + 1] -= s * g.y;
        w2r[mm + 2] -= s * g.z; w2r[mm + 3] -= s * g.w;
      }
    }
    // ---- W2 col copy update: W2[q*64+kk][m] -= cl * sum_i Z1[i][.] g2[i][m]
#pragma unroll
    for (int i = 0; i < 16; ++i) {
      const float s = cl * sg2[i * 68 + m];
#pragma unroll
      for (int kk = 0; kk < 64; kk += 4) {
        float4 z = *(const float4*)&sZ1[i * 260 + q * 64 + kk];
        w2c[kk]     -= s * z.x; w2c[kk + 1] -= s * z.y;
        w2c[kk + 2] -= s * z.z; w2c[kk + 3] -= s * z.w;
      }
    }
    __syncthreads();  // protect sXB/sXC/sZ1/sg2/sRed before next chunk
  }
}

// ---------------------------------------------------------------------------
// Workspace budget (fp32 floats):
//   bXC  [0,        16777216)   64 MiB   Q projection
//   bXB  [16777216, 33554432)   64 MiB   K projection
//   bZ2b [33554432, 50331648)   64 MiB   scan output
//   bCo  [50331648, 50593792)    1 MiB   coeff table
// total 193 MiB.  XA (V projection) lives in d_out: gemm(V)->d_out,
// scan reads it, final gemm overwrites d_out.  Stream-ordered, safe.
// ---------------------------------------------------------------------------
extern "C" void kernel_launch(void* const* d_in, const int* in_sizes, int n_in,
                              void* d_out, int out_size, void* d_ws, size_t ws_size,
                              hipStream_t stream)
{
  const float* H    = (const float*)d_in[0];
  const float* Wq   = (const float*)d_in[1];
  const float* Wk   = (const float*)d_in[2];
  const float* Wv   = (const float*)d_in[3];
  const float* Wo   = (const float*)d_in[4];
  const float* Wil  = (const float*)d_in[5];
  const float* bil  = (const float*)d_in[6];
  const float* W1   = (const float*)d_in[7];
  const float* W2   = (const float*)d_in[8];
  float* out        = (float*)d_out;

  float* ws    = (float*)d_ws;
  float* bXC   = ws;                       // Q proj
  float* bXB   = ws + 16777216;            // K proj
  float* bZ2b  = ws + 33554432;            // scan output
  float* bCo   = ws + 50331648;            // coeff [B][NH][NC][CS]
  float* bXA   = out;                      // V proj lives in d_out until final GEMM

  const int M = Bsz * Lsz, N = Csz, K = Csz;
  dim3 gg(N / 64, M / 64);
  dim3 bb(256);

  gemm64<<<gg, bb, 0, stream>>>(H, Wq, bXC, M, N, K);
  gemm64<<<gg, bb, 0, stream>>>(H, Wk, bXB, M, N, K);
  gemm64<<<gg, bb, 0, stream>>>(H, Wv, bXA, M, N, K);
  ilr_coeff<<<M / 4, 256, 0, stream>>>(H, Wil, bil, bCo);
  ttt_scan<<<Bsz * NHsz, 256, 0, stream>>>(bXA, bXB, bXC, bCo, W1, W2, bZ2b);
  gemm64<<<gg, bb, 0, stream>>>(bZ2b, Wo, out, M, N, K);
}

// Round 3
// 11774.245 us; speedup vs baseline: 4.6022x; 4.6022x over previous
//
#include <hip/hip_runtime.h>

#define Bsz  4
#define Lsz  4096
#define Csz  1024
#define NHsz 16
#define CSsz 16
#define HFsz 64
#define HF4sz 256
#define NCsz 256

// ---------------------------------------------------------------------------
// fp32 GEMM: C[M,N] = A[M,K] @ B[K,N].  64x64 tile, BK=16, 4x4 microtile.
// ---------------------------------------------------------------------------
__global__ __launch_bounds__(256)
void gemm64(const float* __restrict__ A, const float* __restrict__ Bm,
            float* __restrict__ Cm, int M, int N, int K)
{
  __shared__ __attribute__((aligned(16))) float As[16][68];
  __shared__ __attribute__((aligned(16))) float Bs[16][64];
  const int t  = threadIdx.x;
  const int tx = t & 15, ty = t >> 4;
  const int row0 = blockIdx.y * 64, col0 = blockIdx.x * 64;
  const int ar = t >> 2, ak = (t & 3) * 4;
  const int bk = t >> 4, bc = (t & 15) * 4;
  float acc[4][4] = {};

  for (int k0 = 0; k0 < K; k0 += 16) {
    float4 a4 = *(const float4*)&A[(size_t)(row0 + ar) * K + k0 + ak];
    float4 b4 = *(const float4*)&Bm[(size_t)(k0 + bk) * N + col0 + bc];
    As[ak + 0][ar] = a4.x; As[ak + 1][ar] = a4.y;
    As[ak + 2][ar] = a4.z; As[ak + 3][ar] = a4.w;
    *(float4*)&Bs[bk][bc] = b4;
    __syncthreads();
#pragma unroll
    for (int kk = 0; kk < 16; ++kk) {
      float4 av = *(const float4*)&As[kk][ty * 4];
      float4 bv = *(const float4*)&Bs[kk][tx * 4];
      acc[0][0] += av.x * bv.x; acc[0][1] += av.x * bv.y;
      acc[0][2] += av.x * bv.z; acc[0][3] += av.x * bv.w;
      acc[1][0] += av.y * bv.x; acc[1][1] += av.y * bv.y;
      acc[1][2] += av.y * bv.z; acc[1][3] += av.y * bv.w;
      acc[2][0] += av.z * bv.x; acc[2][1] += av.z * bv.y;
      acc[2][2] += av.z * bv.z; acc[2][3] += av.z * bv.w;
      acc[3][0] += av.w * bv.x; acc[3][1] += av.w * bv.y;
      acc[3][2] += av.w * bv.z; acc[3][3] += av.w * bv.w;
    }
    __syncthreads();
  }
#pragma unroll
  for (int r = 0; r < 4; ++r) {
    float4 v = make_float4(acc[r][0], acc[r][1], acc[r][2], acc[r][3]);
    *(float4*)&Cm[(size_t)(row0 + ty * 4 + r) * N + col0 + tx * 4] = v;
  }
}

// ---------------------------------------------------------------------------
// ilr -> coeff table
// ---------------------------------------------------------------------------
__global__ __launch_bounds__(256)
void ilr_coeff(const float* __restrict__ H, const float* __restrict__ Wil,
               const float* __restrict__ bil, float* __restrict__ coeff)
{
  __shared__ float sRow[4][1024];
  __shared__ float sP[4][16][17];
  const int t = threadIdx.x;
  const size_t r0 = (size_t)blockIdx.x * 4;
  for (int rr = 0; rr < 4; ++rr)
    for (int c = t; c < 1024; c += 256)
      sRow[rr][c] = H[(r0 + rr) * 1024 + c];
  __syncthreads();
  const int hh = t & 15, sl = t >> 4;
  for (int rr = 0; rr < 4; ++rr) {
    float acc = 0.f;
    for (int kk = 0; kk < 64; ++kk)
      acc += sRow[rr][sl * 64 + kk] * Wil[(sl * 64 + kk) * 16 + hh];
    sP[rr][sl][hh] = acc;
  }
  __syncthreads();
  if (t < 64) {
    const int rr = t >> 4, h2 = t & 15;
    float s = 0.f;
    for (int sl2 = 0; sl2 < 16; ++sl2) s += sP[rr][sl2][h2];
    s += bil[h2];
    const float sig = 1.f / (1.f + expf(-s));
    const int r  = (int)(r0 + rr);
    const int b  = r >> 12, l = r & 4095, nc = l >> 4, cs = l & 15;
    coeff[((b * 16 + h2) * NCsz + nc) * CSsz + cs] = sig / ((float)(cs + 1) * 64.0f);
  }
}

// ---------------------------------------------------------------------------
// TTT scan, wave-specialized.  One block per (b,h); 512 threads = 8 waves.
//   A-group (t<256):  w1[64] regs  = W1[k][n], n = t.     (~90 VGPR)
//   B-group (t>=256): w2r[64] regs = W2[n][mm], n = t-256 (row copy)
//                     w2c[64] regs = W2[q*64+kk][m], m=t&63, q=(t>>6)&3
// Phases (8 barriers/chunk); g1 and Z2/Z2b partials share sTmp (disjoint
// live ranges).  All hot LDS loops: lane-consecutive or wave-broadcast.
// ---------------------------------------------------------------------------
__global__ __launch_bounds__(512, 2)
void ttt_scan(const float* __restrict__ XA, const float* __restrict__ XBuf,
              const float* __restrict__ XCbuf, const float* __restrict__ coeff,
              const float* __restrict__ W1g, const float* __restrict__ W2g,
              float* __restrict__ Out)
{
  __shared__ __attribute__((aligned(16))) float sXB[16 * 68];
  __shared__ __attribute__((aligned(16))) float sXC[16 * 68];
  __shared__ __attribute__((aligned(16))) float sg2[16 * 68];
  __shared__ __attribute__((aligned(16))) float sZ1[16 * 260];
  __shared__ __attribute__((aligned(16))) float sZ1b[16 * 260];
  __shared__ __attribute__((aligned(16))) float sTmp[4096]; // [4][16][64] partials | [16][256] g1
  __shared__ float sA1[16 * 17];
  __shared__ float sA2[16 * 17];
  __shared__ float sCo[16];

  const int t   = threadIdx.x;
  const int bh  = blockIdx.x;             // 0..63
  const int b   = bh >> 4, h = bh & 15;
  const bool isA = (t < 256);
  const int n   = t & 255;                // A: W1 column / B: W2 row
  const int m   = t & 63, q = (t >> 6) & 3;

  float w1[64];    // A only
  float w2r[64];   // B only
  float w2c[64];   // B only

  const float* W1h = W1g + h * HFsz * HF4sz;
  const float* W2h = W2g + h * HF4sz * HFsz;
  if (isA) {
#pragma unroll
    for (int k = 0; k < 64; ++k) w1[k] = W1h[k * 256 + n];
  } else {
#pragma unroll
    for (int mm = 0; mm < 64; ++mm) w2r[mm] = W2h[n * 64 + mm];
#pragma unroll
    for (int kk = 0; kk < 64; ++kk) w2c[kk] = W2h[(q * 64 + kk) * 64 + m];
  }

#pragma unroll 1
  for (int nc = 0; nc < NCsz; ++nc) {
    const int cb = (b * Lsz + nc * CSsz) * Csz + h * HFsz;

    // ---- P0: stage XB (A) / XC (B), coeff -------------------------------
    {
      const int row = n >> 4, col4 = (n & 15) * 4;
      const float* src = isA ? XBuf : XCbuf;
      float*       dst = isA ? sXB : sXC;
      float4 v = *(const float4*)&src[cb + row * 1024 + col4];
      *(float4*)&dst[row * 68 + col4] = v;
      if (t < 16) sCo[t] = coeff[(bh * NCsz + nc) * CSsz + t];
    }
    __syncthreads();
    const float cl = sCo[15];

    // ---- P1: A: Z1 = XB@W1 -> sZ1   | B: Attn1 = tril(XC@XB^T) ----------
    if (isA) {
#pragma unroll
      for (int i = 0; i < 16; ++i) {
        float acc = 0.f;
#pragma unroll
        for (int k = 0; k < 64; k += 4) {
          float4 x = *(const float4*)&sXB[i * 68 + k];
          acc += x.x * w1[k] + x.y * w1[k + 1] + x.z * w1[k + 2] + x.w * w1[k + 3];
        }
        sZ1[i * 260 + n] = acc;
      }
    } else {
      const int ia = (t - 256) >> 4, ja = t & 15;
      float acc = 0.f;
      if (ja <= ia)
        for (int k = 0; k < 64; ++k) acc += sXC[ia * 68 + k] * sXB[ja * 68 + k];
      sA1[ia * 17 + ja] = acc;
    }
    __syncthreads();

    // ---- P2: A: z1bp = XC@W1 -> sZ1b | B: Z2 partials -> sTmp -----------
    if (isA) {
#pragma unroll
      for (int i = 0; i < 16; ++i) {
        float acc = 0.f;
#pragma unroll
        for (int k = 0; k < 64; k += 4) {
          float4 x = *(const float4*)&sXC[i * 68 + k];
          acc += x.x * w1[k] + x.y * w1[k + 1] + x.z * w1[k + 2] + x.w * w1[k + 3];
        }
        sZ1b[i * 260 + n] = acc;
      }
    } else {
#pragma unroll
      for (int i = 0; i < 16; ++i) {
        float acc = 0.f;
#pragma unroll
        for (int kk = 0; kk < 64; kk += 4) {
          float4 z = *(const float4*)&sZ1[i * 260 + q * 64 + kk];
          acc += z.x * w2c[kk] + z.y * w2c[kk + 1] + z.z * w2c[kk + 2] + z.w * w2c[kk + 3];
        }
        sTmp[q * 1024 + i * 64 + m] = acc;
      }
    }
    __syncthreads();

    // ---- P3: all: g2 = reduce(Z2 partials) - XA -> sg2 ------------------
    {
      const int mm = t & 63, ib = t >> 6;   // ib 0..7
#pragma unroll
      for (int r = 0; r < 2; ++r) {
        const int i = ib + 8 * r;
        float v = sTmp[i * 64 + mm] + sTmp[1024 + i * 64 + mm]
                + sTmp[2048 + i * 64 + mm] + sTmp[3072 + i * 64 + mm];
        v -= XA[cb + i * 1024 + mm];
        sg2[i * 68 + mm] = v;
      }
    }
    __syncthreads();

    // ---- P4: B: g1 = g2@W2^T -> sTmp[16][256] ---------------------------
    if (!isA) {
#pragma unroll
      for (int i = 0; i < 16; ++i) {
        float acc = 0.f;
#pragma unroll
        for (int mm = 0; mm < 64; mm += 4) {
          float4 g = *(const float4*)&sg2[i * 68 + mm];
          acc += g.x * w2r[mm] + g.y * w2r[mm + 1] + g.z * w2r[mm + 2] + g.w * w2r[mm + 3];
        }
        sTmp[i * 256 + n] = acc;
      }
    }
    __syncthreads();

    // ---- P5: A: Z1b finalize + W1 update | B: W2 row update -------------
    if (isA) {
#pragma unroll
      for (int i = 0; i < 16; ++i) {
        float at = 0.f;
#pragma unroll
        for (int j = 0; j < 16; ++j)
          if (j <= i) at += sA1[i * 17 + j] * sTmp[j * 256 + n];
        sZ1b[i * 260 + n] -= sCo[i] * at;
      }
#pragma unroll
      for (int i = 0; i < 16; ++i) {
        const float s = cl * sTmp[i * 256 + n];
#pragma unroll
        for (int k = 0; k < 64; k += 4) {
          float4 x = *(const float4*)&sXB[i * 68 + k];
          w1[k]     -= s * x.x; w1[k + 1] -= s * x.y;
          w1[k + 2] -= s * x.z; w1[k + 3] -= s * x.w;
        }
      }
    } else {
#pragma unroll
      for (int i = 0; i < 16; ++i) {
        const float s = cl * sZ1[i * 260 + n];
#pragma unroll
        for (int mm = 0; mm < 64; mm += 4) {
          float4 g = *(const float4*)&sg2[i * 68 + mm];
          w2r[mm]     -= s * g.x; w2r[mm + 1] -= s * g.y;
          w2r[mm + 2] -= s * g.z; w2r[mm + 3] -= s * g.w;
        }
      }
    }
    __syncthreads();

    // ---- P6: A: Attn2 = tril(Z1b@Z1^T) | B: Z2b partials -> sTmp --------
    if (isA) {
      const int ia = n >> 4, ja = n & 15;
      float acc = 0.f;
      if (ja <= ia) {
        for (int kk = 0; kk < 256; kk += 4) {
          float4 a = *(const float4*)&sZ1b[ia * 260 + kk];
          float4 z = *(const float4*)&sZ1[ja * 260 + kk];
          acc += a.x * z.x + a.y * z.y + a.z * z.z + a.w * z.w;
        }
      }
      sA2[ia * 17 + ja] = acc;
    } else {
#pragma unroll
      for (int i = 0; i < 16; ++i) {
        float acc = 0.f;
#pragma unroll
        for (int kk = 0; kk < 64; kk += 4) {
          float4 z = *(const float4*)&sZ1b[i * 260 + q * 64 + kk];
          acc += z.x * w2c[kk] + z.y * w2c[kk + 1] + z.z * w2c[kk + 2] + z.w * w2c[kk + 3];
        }
        sTmp[q * 1024 + i * 64 + m] = acc;
      }
    }
    __syncthreads();

    // ---- P7: A: Z2b combine + store | B: W2 col update ------------------
    if (isA) {
      const int q4 = n >> 6, mm = n & 63;
#pragma unroll
      for (int r = 0; r < 4; ++r) {
        const int i = q4 + 4 * r;
        float v = sTmp[i * 64 + mm] + sTmp[1024 + i * 64 + mm]
                + sTmp[2048 + i * 64 + mm] + sTmp[3072 + i * 64 + mm];
        float at = 0.f;
#pragma unroll
        for (int j = 0; j < 16; ++j) at += sA2[i * 17 + j] * sg2[j * 68 + mm];
        Out[cb + i * 1024 + mm] = v - sCo[i] * at;
      }
    } else {
#pragma unroll
      for (int i = 0; i < 16; ++i) {
        const float s = cl * sg2[i * 68 + m];
#pragma unroll
        for (int kk = 0; kk < 64; kk += 4) {
          float4 z = *(const float4*)&sZ1[i * 260 + q * 64 + kk];
          w2c[kk]     -= s * z.x; w2c[kk + 1] -= s * z.y;
          w2c[kk + 2] -= s * z.z; w2c[kk + 3] -= s * z.w;
        }
      }
    }
    __syncthreads();
  }
}

// ---------------------------------------------------------------------------
// Workspace (fp32 floats): bXC [0,16.7M) | bXB [16.7M,33.5M) | bZ2b
// [33.5M,50.3M) | bCo [50.3M,+262k).  193 MiB total.  XA (V proj) lives in
// d_out until the final GEMM overwrites it (stream-ordered, safe).
// ---------------------------------------------------------------------------
extern "C" void kernel_launch(void* const* d_in, const int* in_sizes, int n_in,
                              void* d_out, int out_size, void* d_ws, size_t ws_size,
                              hipStream_t stream)
{
  const float* H    = (const float*)d_in[0];
  const float* Wq   = (const float*)d_in[1];
  const float* Wk   = (const float*)d_in[2];
  const float* Wv   = (const float*)d_in[3];
  const float* Wo   = (const float*)d_in[4];
  const float* Wil  = (const float*)d_in[5];
  const float* bil  = (const float*)d_in[6];
  const float* W1   = (const float*)d_in[7];
  const float* W2   = (const float*)d_in[8];
  float* out        = (float*)d_out;

  float* ws    = (float*)d_ws;
  float* bXC   = ws;
  float* bXB   = ws + 16777216;
  float* bZ2b  = ws + 33554432;
  float* bCo   = ws + 50331648;
  float* bXA   = out;

  const int M = Bsz * Lsz, N = Csz, K = Csz;
  dim3 gg(N / 64, M / 64);
  dim3 bb(256);

  gemm64<<<gg, bb, 0, stream>>>(H, Wq, bXC, M, N, K);
  gemm64<<<gg, bb, 0, stream>>>(H, Wk, bXB, M, N, K);
  gemm64<<<gg, bb, 0, stream>>>(H, Wv, bXA, M, N, K);
  ilr_coeff<<<M / 4, 256, 0, stream>>>(H, Wil, bil, bCo);
  ttt_scan<<<Bsz * NHsz, 512, 0, stream>>>(bXA, bXB, bXC, bCo, W1, W2, bZ2b);
  gemm64<<<gg, bb, 0, stream>>>(bZ2b, Wo, out, M, N, K);
}